// Round 2
// baseline (309.790 us; speedup 1.0000x reference)
//
#include <hip/hip_runtime.h>

#define FEAT    4096
#define NACT    512
#define THREADS 256
#define EPT     16            // elements per thread (FEAT / THREADS)
#define KRANK   (FEAT - NACT) // ascending 0-indexed rank of smallest kept elem = 3584

// Order-preserving float32 -> uint32 key transform:
// ascending uint order == ascending float order (handles negatives).
__device__ __forceinline__ unsigned f2key(float f) {
    unsigned b = __float_as_uint(f);
    return (b & 0x80000000u) ? ~b : (b | 0x80000000u);
}

__global__ __launch_bounds__(THREADS) void normactive_kernel(
        const float* __restrict__ in, float* __restrict__ out) {
    const int row = blockIdx.x;
    const int tid = threadIdx.x;
    const float* rp = in  + (size_t)row * FEAT;
    float*       op = out + (size_t)row * FEAT;

    // ---- Load the full row into registers: 4x float4 per thread, coalesced.
    // float4 chunk c at float4-index c*256+tid -> element idx (c*256+tid)*4 + j
    float4 v[4];
    #pragma unroll
    for (int c = 0; c < 4; ++c)
        v[c] = reinterpret_cast<const float4*>(rp)[c * THREADS + tid];

    unsigned key[EPT];
    #pragma unroll
    for (int c = 0; c < 4; ++c) {
        key[4*c + 0] = f2key(v[c].x);
        key[4*c + 1] = f2key(v[c].y);
        key[4*c + 2] = f2key(v[c].z);
        key[4*c + 3] = f2key(v[c].w);
    }

    // ---- 4-pass radix select (8 bits / pass, MSB first) for the key of
    // ascending rank KRANK (= value of the smallest kept element).
    __shared__ unsigned hist[256];
    __shared__ unsigned s_digit;
    __shared__ unsigned s_kk;

    unsigned prefix = 0;   // high bits of the target key found so far
    unsigned kk = KRANK;   // rank within the surviving candidate set

    for (int pass = 0; pass < 4; ++pass) {
        const int shift = 24 - 8 * pass;

        hist[tid] = 0;
        __syncthreads();

        #pragma unroll
        for (int e = 0; e < EPT; ++e) {
            unsigned k = key[e];
            bool cand = (pass == 0) || ((k >> (shift + 8)) == prefix);
            if (cand)
                atomicAdd(&hist[(k >> shift) & 255u], 1u);
        }
        __syncthreads();

        if (tid == 0) {
            unsigned run = 0;
            #pragma unroll 1
            for (int d = 0; d < 256; ++d) {
                unsigned c = hist[d];
                if (kk < run + c) { s_digit = (unsigned)d; s_kk = kk - run; break; }
                run += c;
            }
        }
        __syncthreads();

        prefix = (prefix << 8) | s_digit;
        kk = s_kk;
    }

    const unsigned K = prefix;  // full 32-bit key of the rank-3584 element

    // ---- Tie resolution at the boundary value.
    // Reference = stable ascending argsort, keep tail slice -> among elements
    // equal to the boundary value, the LARGEST indices are kept.
    __shared__ unsigned s_cnt[2];   // [0] = #{key > K}, [1] = #{key == K}
    __shared__ unsigned s_f;
    if (tid < 2) s_cnt[tid] = 0;
    __syncthreads();

    unsigned lg = 0, le = 0;
    #pragma unroll
    for (int e = 0; e < EPT; ++e) {
        lg += (key[e] > K);
        le += (key[e] == K);
    }
    if (lg) atomicAdd(&s_cnt[0], lg);
    if (le) atomicAdd(&s_cnt[1], le);
    __syncthreads();

    const unsigned nG  = s_cnt[0];
    const unsigned nEq = s_cnt[1];
    const unsigned kEq = NACT - nG;   // how many ==K elements to keep (>=1)

    int tIdx = 0;                     // keep ==K elements with idx >= tIdx
    if (kEq != nEq) {
        // Block-uniform binary search: largest t with #{key==K && idx>=t} >= kEq.
        int lo = 0, hi = FEAT;
        while (lo < hi) {
            int mid = (lo + hi + 1) >> 1;
            if (tid == 0) s_f = 0;
            __syncthreads();
            unsigned c = 0;
            #pragma unroll
            for (int e = 0; e < EPT; ++e) {
                int cc = e >> 2, j = e & 3;
                int idx = cc * (THREADS * 4) + tid * 4 + j;
                if (key[e] == K && idx >= mid) ++c;
            }
            if (c) atomicAdd(&s_f, c);
            __syncthreads();
            if (s_f >= kEq) lo = mid; else hi = mid - 1;
            __syncthreads();   // protect s_f reset next iteration
        }
        tIdx = lo;
    }

    // ---- Output pass: keep iff key > K, or key == K with idx >= tIdx.
    #pragma unroll
    for (int c = 0; c < 4; ++c) {
        float4 o;
        int base = c * (THREADS * 4) + tid * 4;
        o.x = (key[4*c+0] > K || (key[4*c+0] == K && base + 0 >= tIdx)) ? v[c].x * 8.0f : 0.0f;
        o.y = (key[4*c+1] > K || (key[4*c+1] == K && base + 1 >= tIdx)) ? v[c].y * 8.0f : 0.0f;
        o.z = (key[4*c+2] > K || (key[4*c+2] == K && base + 2 >= tIdx)) ? v[c].z * 8.0f : 0.0f;
        o.w = (key[4*c+3] > K || (key[4*c+3] == K && base + 3 >= tIdx)) ? v[c].w * 8.0f : 0.0f;
        reinterpret_cast<float4*>(op)[c * THREADS + tid] = o;
    }
}

extern "C" void kernel_launch(void* const* d_in, const int* in_sizes, int n_in,
                              void* d_out, int out_size, void* d_ws, size_t ws_size,
                              hipStream_t stream) {
    const float* feat = (const float*)d_in[0];
    float* out = (float*)d_out;
    const int batch = in_sizes[0] / FEAT;  // 8192
    normactive_kernel<<<batch, THREADS, 0, stream>>>(feat, out);
}

// Round 3
// 74.484 us; speedup vs baseline: 4.1592x; 4.1592x over previous
//
#include <hip/hip_runtime.h>

#define FEAT    4096
#define NACT    512
#define THREADS 256
#define EPT     16            // elements per thread (FEAT / THREADS)
#define KRANK   (FEAT - NACT) // ascending 0-indexed rank of smallest kept elem = 3584

// Order-preserving float32 -> uint32 key transform:
// ascending uint order == ascending float order (handles negatives).
__device__ __forceinline__ unsigned f2key(float f) {
    unsigned b = __float_as_uint(f);
    return (b & 0x80000000u) ? ~b : (b | 0x80000000u);
}

__global__ __launch_bounds__(THREADS) void normactive_kernel(
        const float* __restrict__ in, float* __restrict__ out) {
    const int row = blockIdx.x;
    const int tid = threadIdx.x;
    const int wid  = tid >> 6;   // wave id (0..3)
    const int lane = tid & 63;
    const float* rp = in  + (size_t)row * FEAT;
    float*       op = out + (size_t)row * FEAT;

    // ---- Load the full row into registers: 4x float4 per thread, coalesced.
    float4 v[4];
    #pragma unroll
    for (int c = 0; c < 4; ++c)
        v[c] = reinterpret_cast<const float4*>(rp)[c * THREADS + tid];

    unsigned key[EPT];
    #pragma unroll
    for (int c = 0; c < 4; ++c) {
        key[4*c + 0] = f2key(v[c].x);
        key[4*c + 1] = f2key(v[c].y);
        key[4*c + 2] = f2key(v[c].z);
        key[4*c + 3] = f2key(v[c].w);
    }

    // ---- 4-pass radix select (8 bits / pass, MSB first).
    // Per-wave privatized histograms to cut same-address atomic serialization.
    __shared__ unsigned hist4[4][256];
    __shared__ unsigned wsum[4];
    __shared__ unsigned s_digit, s_kk, s_cnt, s_f;

    unsigned prefix = 0;   // high bits of the target key found so far
    unsigned kk = KRANK;   // rank within surviving candidate set
    unsigned nEq = 0;      // after last pass: #{key == K}

    for (int pass = 0; pass < 4; ++pass) {
        const int shift = 24 - 8 * pass;

        #pragma unroll
        for (int w = 0; w < 4; ++w) hist4[w][tid] = 0;
        __syncthreads();

        #pragma unroll
        for (int e = 0; e < EPT; ++e) {
            unsigned k = key[e];
            bool cand = (pass == 0) || ((k >> (shift + 8)) == prefix);
            if (cand)
                atomicAdd(&hist4[wid][(k >> shift) & 255u], 1u);
        }
        __syncthreads();

        // Parallel rank-find: thread `tid` owns bin `tid`.
        unsigned c = hist4[0][tid] + hist4[1][tid] + hist4[2][tid] + hist4[3][tid];

        // Wave-level inclusive scan over 64 bins via shfl_up.
        unsigned inc = c;
        #pragma unroll
        for (int off = 1; off < 64; off <<= 1) {
            unsigned n = __shfl_up(inc, (unsigned)off, 64);
            if (lane >= off) inc += n;
        }
        if (lane == 63) wsum[wid] = inc;
        __syncthreads();

        unsigned base = 0;
        #pragma unroll
        for (int w = 0; w < 3; ++w)
            if (w < wid) base += wsum[w];

        unsigned incl = base + inc;   // inclusive cumsum over bins <= tid
        unsigned excl = incl - c;     // exclusive
        if (kk >= excl && kk < incl) {   // exactly one thread (c > 0 there)
            s_digit = (unsigned)tid;
            s_kk    = kk - excl;
            s_cnt   = c;
        }
        __syncthreads();

        prefix = (prefix << 8) | s_digit;
        kk  = s_kk;
        nEq = s_cnt;
        // next write to s_* is two barriers away (zero + fill) -> safe
    }

    const unsigned K = prefix;       // full 32-bit key of the rank-KRANK element
    const unsigned kEq = nEq - kk;   // how many ==K elements to keep (largest indices)

    // ---- Tie resolution (rare: only when kk > 0, i.e. a duplicate straddles
    // the boundary). Reference = stable ascending argsort, keep tail slice ->
    // among elements equal to the boundary value, LARGEST indices are kept.
    int tIdx = 0;                    // keep ==K elements with idx >= tIdx
    if (kk > 0) {
        int lo = 0, hi = FEAT;
        while (lo < hi) {
            int mid = (lo + hi + 1) >> 1;
            if (tid == 0) s_f = 0;
            __syncthreads();
            unsigned cnt = 0;
            #pragma unroll
            for (int e = 0; e < EPT; ++e) {
                int cc = e >> 2, j = e & 3;
                int idx = cc * (THREADS * 4) + tid * 4 + j;
                if (key[e] == K && idx >= mid) ++cnt;
            }
            if (cnt) atomicAdd(&s_f, cnt);
            __syncthreads();
            if (s_f >= kEq) lo = mid; else hi = mid - 1;
            __syncthreads();
        }
        tIdx = lo;
    }

    // ---- Output pass: keep iff key > K, or key == K with idx >= tIdx.
    #pragma unroll
    for (int c = 0; c < 4; ++c) {
        float4 o;
        int base2 = c * (THREADS * 4) + tid * 4;
        o.x = (key[4*c+0] > K || (key[4*c+0] == K && base2 + 0 >= tIdx)) ? v[c].x * 8.0f : 0.0f;
        o.y = (key[4*c+1] > K || (key[4*c+1] == K && base2 + 1 >= tIdx)) ? v[c].y * 8.0f : 0.0f;
        o.z = (key[4*c+2] > K || (key[4*c+2] == K && base2 + 2 >= tIdx)) ? v[c].z * 8.0f : 0.0f;
        o.w = (key[4*c+3] > K || (key[4*c+3] == K && base2 + 3 >= tIdx)) ? v[c].w * 8.0f : 0.0f;
        reinterpret_cast<float4*>(op)[c * THREADS + tid] = o;
    }
}

extern "C" void kernel_launch(void* const* d_in, const int* in_sizes, int n_in,
                              void* d_out, int out_size, void* d_ws, size_t ws_size,
                              hipStream_t stream) {
    const float* feat = (const float*)d_in[0];
    float* out = (float*)d_out;
    const int batch = in_sizes[0] / FEAT;  // 8192
    normactive_kernel<<<batch, THREADS, 0, stream>>>(feat, out);
}

// Round 4
// 60.799 us; speedup vs baseline: 5.0953x; 1.2251x over previous
//
#include <hip/hip_runtime.h>

#define FEAT    4096
#define NACT    512
#define THREADS 256
#define EPT     16            // elements per thread
#define KRANK   (FEAT - NACT) // ascending 0-indexed rank of smallest kept elem = 3584
#define NBIN    4096          // 12-bit first (and only) histogram pass

// Order-preserving float32 <-> uint32 key transform.
__device__ __forceinline__ unsigned f2key(float f) {
    unsigned b = __float_as_uint(f);
    return (b & 0x80000000u) ? ~b : (b | 0x80000000u);
}
__device__ __forceinline__ float key2f(unsigned k) {
    unsigned b = (k & 0x80000000u) ? (k & 0x7fffffffu) : ~k;
    return __uint_as_float(b);
}

// Swizzled LDS slot for bin: thread t later reads bins [16t,16t+16) at
// L=(i<<8)|t -> for fixed i, lanes hit consecutive addresses (conflict-free).
__device__ __forceinline__ unsigned binslot(unsigned bin) {
    return ((bin & 15u) << 8) | (bin >> 4);
}

__global__ __launch_bounds__(THREADS) void normactive_kernel(
        const float* __restrict__ in, float* __restrict__ out) {
    const int row  = blockIdx.x;
    const int tid  = threadIdx.x;
    const int wid  = tid >> 6;
    const int lane = tid & 63;
    const float* rp = in  + (size_t)row * FEAT;
    float*       op = out + (size_t)row * FEAT;

    __shared__ unsigned buf[NBIN];   // histogram, then reused as candidate array
    __shared__ unsigned wsum[4];
    __shared__ unsigned s_P, s_kk, s_cnt, s_T, s_n;

    // ---- Load row, convert to keys (values reconstructed later from keys).
    unsigned key[EPT];
    #pragma unroll
    for (int c = 0; c < 4; ++c) {
        float4 v = reinterpret_cast<const float4*>(rp)[c * THREADS + tid];
        key[4*c + 0] = f2key(v.x);
        key[4*c + 1] = f2key(v.y);
        key[4*c + 2] = f2key(v.z);
        key[4*c + 3] = f2key(v.w);
    }

    // ---- Zero histogram (4096 bins) with uint4 stores.
    uint4 z; z.x = z.y = z.z = z.w = 0u;
    #pragma unroll
    for (int i = 0; i < 4; ++i)
        reinterpret_cast<uint4*>(buf)[i * THREADS + tid] = z;
    if (tid == 0) s_n = 0;
    __syncthreads();

    // ---- Histogram on top 12 bits (swizzled slots).
    #pragma unroll
    for (int e = 0; e < EPT; ++e)
        atomicAdd(&buf[binslot(key[e] >> 20)], 1u);
    __syncthreads();

    // ---- Scan: thread t owns bins [16t, 16t+16). Sum them (conflict-free reads).
    unsigned tot = 0;
    #pragma unroll
    for (int i = 0; i < 16; ++i)
        tot += buf[(i << 8) | tid];

    // Wave inclusive scan + 4-wave combine.
    unsigned inc = tot;
    #pragma unroll
    for (int off = 1; off < 64; off <<= 1) {
        unsigned n = __shfl_up(inc, (unsigned)off, 64);
        if (lane >= off) inc += n;
    }
    if (lane == 63) wsum[wid] = inc;
    __syncthreads();
    unsigned base = 0;
    #pragma unroll
    for (int w = 0; w < 3; ++w)
        if (w < wid) base += wsum[w];
    const unsigned excl = base + inc - tot;  // exclusive cumsum at bin 16*tid

    // ---- Locate the bin containing global ascending rank KRANK.
    if ((unsigned)KRANK >= excl && (unsigned)KRANK < excl + tot) {
        unsigned run = excl;
        #pragma unroll
        for (int i = 0; i < 16; ++i) {
            unsigned ci = buf[(i << 8) | tid];   // re-read (saves 16 VGPRs)
            if ((unsigned)KRANK >= run && (unsigned)KRANK < run + ci) {
                s_P   = (unsigned)(tid * 16 + i);
                s_kk  = (unsigned)KRANK - run;
                s_cnt = ci;
            }
            run += ci;
        }
    }
    __syncthreads();  // also: all threads done with histogram -> buf reusable

    const unsigned P   = s_P;     // 12-bit prefix of the boundary element
    const unsigned kk  = s_kk;    // rank within the boundary bin
    const unsigned cnt = s_cnt;   // boundary-bin population

    // ---- Compact boundary-bin candidates as packed (key<<12)|idx.
    // Packed order == (value, idx) lexicographic == reference stable-sort
    // tie-breaking (largest indices kept), and all packed values are distinct.
    #pragma unroll
    for (int e = 0; e < EPT; ++e) {
        int cc = e >> 2, j = e & 3;
        unsigned idx = (unsigned)(cc * (THREADS * 4) + tid * 4 + j);
        if ((key[e] >> 20) == P) {
            unsigned pos = atomicAdd(&s_n, 1u);
            buf[pos] = (key[e] << 12) | idx;
        }
    }
    __syncthreads();

    // ---- Rank-select: packed value of ascending rank kk among buf[0..cnt).
    // All threads read the same LDS address per iteration -> broadcast.
    for (unsigned slot = tid; slot < cnt; slot += THREADS) {
        unsigned myv = buf[slot];
        unsigned r = 0, j = 0;
        for (; j + 4 <= cnt; j += 4) {
            uint4 q = reinterpret_cast<const uint4*>(buf)[j >> 2];
            r += (q.x < myv) + (q.y < myv) + (q.z < myv) + (q.w < myv);
        }
        for (; j < cnt; ++j) r += (buf[j] < myv);
        if (r == kk) s_T = myv;   // exactly one thread matches
    }
    __syncthreads();
    const unsigned T = s_T;

    // ---- Output: keep iff top12 > P, or top12 == P and packed >= T.
    #pragma unroll
    for (int cb = 0; cb < 4; ++cb) {
        const int bidx = cb * (THREADS * 4) + tid * 4;
        float4 o;
        {
            unsigned k = key[4*cb + 0], t12 = k >> 20;
            bool keep = (t12 > P) || (t12 == P && ((k << 12) | (unsigned)(bidx + 0)) >= T);
            o.x = keep ? key2f(k) * 8.0f : 0.0f;
        }
        {
            unsigned k = key[4*cb + 1], t12 = k >> 20;
            bool keep = (t12 > P) || (t12 == P && ((k << 12) | (unsigned)(bidx + 1)) >= T);
            o.y = keep ? key2f(k) * 8.0f : 0.0f;
        }
        {
            unsigned k = key[4*cb + 2], t12 = k >> 20;
            bool keep = (t12 > P) || (t12 == P && ((k << 12) | (unsigned)(bidx + 2)) >= T);
            o.z = keep ? key2f(k) * 8.0f : 0.0f;
        }
        {
            unsigned k = key[4*cb + 3], t12 = k >> 20;
            bool keep = (t12 > P) || (t12 == P && ((k << 12) | (unsigned)(bidx + 3)) >= T);
            o.w = keep ? key2f(k) * 8.0f : 0.0f;
        }
        reinterpret_cast<float4*>(op)[cb * THREADS + tid] = o;
    }
}

extern "C" void kernel_launch(void* const* d_in, const int* in_sizes, int n_in,
                              void* d_out, int out_size, void* d_ws, size_t ws_size,
                              hipStream_t stream) {
    const float* feat = (const float*)d_in[0];
    float* out = (float*)d_out;
    const int batch = in_sizes[0] / FEAT;  // 8192
    normactive_kernel<<<batch, THREADS, 0, stream>>>(feat, out);
}

// Round 5
// 45.580 us; speedup vs baseline: 6.7967x; 1.3339x over previous
//
#include <hip/hip_runtime.h>

#define FEAT    4096
#define NACT    512
#define THREADS 256
#define EPT     16
#define KRANK   (FEAT - NACT)   // 3584: ascending rank of smallest kept elem
#define FLO     0.8f
#define FHI     1.5f
#define RBINS   1024
#define MAXCAND 64

// Order-preserving float32 <-> uint32 key transform (fallback path only).
__device__ __forceinline__ unsigned f2key(float f) {
    unsigned b = __float_as_uint(f);
    return (b & 0x80000000u) ? ~b : (b | 0x80000000u);
}
__device__ __forceinline__ float key2f(unsigned k) {
    unsigned b = (k & 0x80000000u) ? (k & 0x7fffffffu) : ~k;
    return __uint_as_float(b);
}

__global__ __launch_bounds__(THREADS, 8) void normactive_kernel(
        const float* __restrict__ in, float* __restrict__ out) {
    const int tid  = threadIdx.x;
    const int wid  = tid >> 6;
    const int lane = tid & 63;
    const float* rp = in  + (size_t)blockIdx.x * FEAT;
    float*       op = out + (size_t)blockIdx.x * FEAT;

    __shared__ __align__(16) unsigned buf[4096];   // 1024-bin range hist; fallback 4096-bin hist + compact
    __shared__ unsigned long long cand[MAXCAND];
    __shared__ unsigned wsum[4];
    __shared__ unsigned s_nhi, s_n, s_B, s_kk, s_cnt, s_tidx;
    __shared__ float s_vb;

    // ---- Load row into registers (coalesced float4).
    float xv[EPT];
    #pragma unroll
    for (int c = 0; c < 4; ++c) {
        float4 t = reinterpret_cast<const float4*>(rp)[c * THREADS + tid];
        xv[4*c+0] = t.x; xv[4*c+1] = t.y; xv[4*c+2] = t.z; xv[4*c+3] = t.w;
    }

    // ---- Zero 1024-bin histogram + counters.
    uint4 z; z.x = z.y = z.z = z.w = 0u;
    reinterpret_cast<uint4*>(buf)[tid] = z;        // 256 * 16B = 1024 words
    if (tid == 0) { s_nhi = 0; s_n = 0; }
    __syncthreads();

    // ---- Classify: count x > FHI; histogram x in (FLO, FHI] into 1024 bins.
    const float invw = (float)RBINS / (FHI - FLO);
    unsigned chi = 0;
    unsigned ub[EPT];                              // per-element bin (0xffffffff = not in range)
    #pragma unroll
    for (int e = 0; e < EPT; ++e) {
        float x = xv[e];
        bool hi = (x > FHI);
        chi += hi ? 1u : 0u;
        unsigned b = 0xffffffffu;
        if (x > FLO && !hi) {
            int bi = (int)((x - FLO) * invw);      // >= 0 since x > FLO; monotone in x
            bi = bi < (RBINS - 1) ? bi : (RBINS - 1);
            b = (unsigned)bi;
            atomicAdd(&buf[bi], 1u);
        }
        ub[e] = b;
    }
    #pragma unroll
    for (int off = 32; off >= 1; off >>= 1)
        chi += __shfl_xor(chi, (unsigned)off, 64);
    if (lane == 0) atomicAdd(&s_nhi, chi);
    __syncthreads();

    const int nHi = (int)s_nhi;

    // ---- Scan: thread t owns bins [4t, 4t+4); one b128 read + wave scan.
    uint4 q = reinterpret_cast<const uint4*>(buf)[tid];
    unsigned s = q.x + q.y + q.z + q.w;
    unsigned inc = s;
    #pragma unroll
    for (int off = 1; off < 64; off <<= 1) {
        unsigned n = __shfl_up(inc, (unsigned)off, 64);
        if (lane >= off) inc += n;
    }
    if (lane == 63) wsum[wid] = inc;
    __syncthreads();
    unsigned base = 0;
    #pragma unroll
    for (int w = 0; w < 3; ++w) if (w < wid) base += wsum[w];
    const int nIn = (int)(wsum[0] + wsum[1] + wsum[2] + wsum[3]);
    const unsigned excl = base + inc - s;          // asc prefix at bin 4*tid (within range region)

    const int nLo  = FEAT - nIn - nHi;
    const int need = NACT - nHi;                   // kept elements still needed from binned region
    const int kkb  = KRANK - nLo;                  // asc rank of boundary within binned region

    // mode: 0 = boundary in an interior bin, 1 = threshold exactly at FHI, 2 = generic fallback
    int mode = (need > 0 && kkb >= 0 && kkb < nIn) ? 0 : ((need == 0) ? 1 : 2);

    if (mode == 0) {
        unsigned bq[4] = {q.x, q.y, q.z, q.w};
        unsigned run = excl;
        #pragma unroll
        for (int i = 0; i < 4; ++i) {
            if ((unsigned)kkb >= run && (unsigned)kkb < run + bq[i]) {
                s_B   = (unsigned)(4 * tid + i);
                s_kk  = (unsigned)kkb - run;
                s_cnt = bq[i];
            }
            run += bq[i];
        }
    }
    __syncthreads();

    if (mode == 0 && s_cnt > MAXCAND) mode = 2;    // uniform

    if (mode == 0) {
        const unsigned B = s_B, kk = s_kk, cnt = s_cnt;
        // Compact boundary-bin candidates as (bits, idx); all in-range values are
        // positive so uint-bit order == float order. (value, idx) lexicographic
        // == reference stable-sort tie rule (largest indices kept).
        #pragma unroll
        for (int e = 0; e < EPT; ++e) {
            if (ub[e] == B) {
                unsigned idx = (unsigned)((e >> 2) * 1024 + tid * 4 + (e & 3));
                unsigned pos = atomicAdd(&s_n, 1u);
                cand[pos] = ((unsigned long long)__float_as_uint(xv[e]) << 32) | idx;
            }
        }
        __syncthreads();
        if (tid < (int)cnt) {
            unsigned long long my = cand[tid];
            unsigned r = 0;
            for (unsigned j = 0; j < cnt; ++j) r += (cand[j] < my) ? 1u : 0u;
            if (r == kk) {                          // exactly one thread matches
                s_vb   = __uint_as_float((unsigned)(my >> 32));
                s_tidx = (unsigned)(my & 0xffffffffu);
            }
        }
    } else if (mode == 1) {
        // Exactly nHi == 512: keep = (x > FHI); no ties kept.
        if (tid == 0) { s_vb = FHI; s_tidx = (unsigned)FEAT; }
    } else {
        // ---- Generic fallback (never taken for this input): 12-bit key hist +
        // compact + rank-select (R4's verified algorithm). Keys recomputed
        // inline from xv so this path adds no VGPR pressure to the hot path.
        #pragma unroll
        for (int i = 0; i < 4; ++i)
            reinterpret_cast<uint4*>(buf)[i * THREADS + tid] = z;
        if (tid == 0) s_n = 0;
        __syncthreads();
        #pragma unroll
        for (int e = 0; e < EPT; ++e)
            atomicAdd(&buf[f2key(xv[e]) >> 20], 1u);
        __syncthreads();
        unsigned tot = 0;
        #pragma unroll
        for (int i = 0; i < 16; ++i) tot += buf[16 * tid + i];
        unsigned inc2 = tot;
        #pragma unroll
        for (int off = 1; off < 64; off <<= 1) {
            unsigned n = __shfl_up(inc2, (unsigned)off, 64);
            if (lane >= off) inc2 += n;
        }
        if (lane == 63) wsum[wid] = inc2;
        __syncthreads();
        unsigned b2 = 0;
        #pragma unroll
        for (int w = 0; w < 3; ++w) if (w < wid) b2 += wsum[w];
        unsigned ex2 = b2 + inc2 - tot;
        if ((unsigned)KRANK >= ex2 && (unsigned)KRANK < ex2 + tot) {
            unsigned run = ex2;
            #pragma unroll
            for (int i = 0; i < 16; ++i) {
                unsigned c = buf[16 * tid + i];
                if ((unsigned)KRANK >= run && (unsigned)KRANK < run + c) {
                    s_B   = (unsigned)(16 * tid + i);
                    s_kk  = (unsigned)KRANK - run;
                    s_cnt = c;
                }
                run += c;
            }
        }
        __syncthreads();
        const unsigned P = s_B, kk2 = s_kk, cnt2 = s_cnt;
        #pragma unroll
        for (int e = 0; e < EPT; ++e) {
            unsigned k = f2key(xv[e]);
            if ((k >> 20) == P) {
                unsigned idx = (unsigned)((e >> 2) * 1024 + tid * 4 + (e & 3));
                unsigned pos = atomicAdd(&s_n, 1u);
                buf[pos] = (k << 12) | idx;
            }
        }
        __syncthreads();
        for (unsigned slot = tid; slot < cnt2; slot += THREADS) {
            unsigned my = buf[slot];
            unsigned r = 0;
            for (unsigned j = 0; j < cnt2; ++j) r += (buf[j] < my) ? 1u : 0u;
            if (r == kk2) {
                s_vb   = key2f((P << 20) | (my >> 12));   // candidates share top-12 bits P
                s_tidx = my & 0xfffu;
            }
        }
    }
    __syncthreads();

    const float vb = s_vb;
    const int   ti = (int)s_tidx;

    // ---- Output: keep iff x > vb, or x == vb with idx >= ti. Exact ×8 scale.
    #pragma unroll
    for (int c = 0; c < 4; ++c) {
        const int bidx = c * 1024 + tid * 4;
        float a0 = xv[4*c+0], a1 = xv[4*c+1], a2 = xv[4*c+2], a3 = xv[4*c+3];
        float4 o;
        o.x = (a0 > vb || (a0 == vb && bidx + 0 >= ti)) ? a0 * 8.0f : 0.0f;
        o.y = (a1 > vb || (a1 == vb && bidx + 1 >= ti)) ? a1 * 8.0f : 0.0f;
        o.z = (a2 > vb || (a2 == vb && bidx + 2 >= ti)) ? a2 * 8.0f : 0.0f;
        o.w = (a3 > vb || (a3 == vb && bidx + 3 >= ti)) ? a3 * 8.0f : 0.0f;
        reinterpret_cast<float4*>(op)[c * THREADS + tid] = o;
    }
}

extern "C" void kernel_launch(void* const* d_in, const int* in_sizes, int n_in,
                              void* d_out, int out_size, void* d_ws, size_t ws_size,
                              hipStream_t stream) {
    const float* feat = (const float*)d_in[0];
    float* out = (float*)d_out;
    const int batch = in_sizes[0] / FEAT;  // 8192
    normactive_kernel<<<batch, THREADS, 0, stream>>>(feat, out);
}